// Round 1
// baseline (26088.446 us; speedup 1.0000x reference)
//
#include <hip/hip_runtime.h>

typedef __attribute__((ext_vector_type(8))) short short8;
typedef __attribute__((ext_vector_type(4))) float f32x4;

#define DT (1.0f/256.0f)
#define NSTEPS 256

__device__ __forceinline__ short f2bf(float f) {
    unsigned u = __float_as_uint(f);
    u = (u + 0x7fffu + ((u >> 16) & 1u)) >> 16;
    return (short)u;
}

__device__ __forceinline__ float fast_tanh(float x) {
    float e = __expf(2.f * x);
    return 1.f - __fdividef(2.f, e + 1.f);
}

// ---------------- weight permutation (A-fragment order, bf16) ----------------
// A-frag for mfma_f32_16x16x32_bf16: lane l holds A[m = l&15][k = kc*32 + (l>>4)*8 + j], j=0..7
__global__ void perm_w0(const float* __restrict__ W0, short* __restrict__ W0p) {
    int i = blockIdx.x * 256 + threadIdx.x;            // 32768 = 16ot*4kc*64*8
    int j = i & 7, l = (i >> 3) & 63, kc = (i >> 9) & 3, ot = i >> 11;
    int row = ot * 16 + (l & 15);
    int col = kc * 32 + ((l >> 4) << 3) + j;
    W0p[i] = f2bf(W0[row * 128 + col]);
}
__global__ void perm_w1(const float* __restrict__ W1, short* __restrict__ W1p) {
    int i = blockIdx.x * 256 + threadIdx.x;            // 131072 = 16ot*8kc*64*8
    int j = i & 7, l = (i >> 3) & 63, kc = (i >> 9) & 7, ot = i >> 12;
    int row = ot * 16 + (l & 15);
    int col = kc * 32 + ((l >> 4) << 3) + j;
    W1p[i] = f2bf(W1[row * 256 + col]);
}
__global__ void perm_w2(const float* __restrict__ W2, short* __restrict__ W2p) {
    int i = blockIdx.x * 256 + threadIdx.x;            // 2064384 = 8ht*63l*8kc*64*8
    int j = i & 7, l = (i >> 3) & 63, kc = (i >> 9) & 7;
    int v = i >> 12;                                   // ht*63 + lv
    int ht = v / 63, lv = v - ht * 63;
    int row = (ht * 16 + (l & 15)) * 63 + lv;          // W2 row = h*63 + l
    int col = kc * 32 + ((l >> 4) << 3) + j;
    W2p[i] = f2bf(W2[row * 256 + col]);
}

// ---------------- y0 = x0 @ l1w^T + l1b ----------------
__global__ void y0_kernel(const float* __restrict__ x0, const float* __restrict__ l1w,
                          const float* __restrict__ l1b, float* __restrict__ y) {
    int i = blockIdx.x * 256 + threadIdx.x;            // 65536
    int b = i >> 7, h = i & 127;
    float s = l1b[h];
    #pragma unroll
    for (int d = 0; d < 8; ++d) s += x0[b * 8 + d] * l1w[h * 8 + d];
    y[i] = s;
}

// ---------------- one RK stage ----------------
// grid 256 = 32 b-groups (16 rows each) x 8 h-tiles (16 h each); 256 threads (4 waves)
template<int STAGE>
__global__ __launch_bounds__(256) void stage_kernel(
    const float* __restrict__ ycur, float* __restrict__ ynext,
    float* __restrict__ kbuf,
    const short* __restrict__ W0p, const short* __restrict__ W1p, const short* __restrict__ W2p,
    const float* __restrict__ b0, const float* __restrict__ b1, const float* __restrict__ b2,
    const float* __restrict__ logsig, int idx)
{
    __shared__ __align__(16) short ysb[16 * 136];   // stage input, bf16, padded stride
    __shared__ __align__(16) short h1b[16 * 264];
    __shared__ __align__(16) short h2b[16 * 264];
    __shared__ float gsh[16 * 65];                  // g[b_local][l]
    __shared__ float b2sh[16 * 65];                 // b2[h_local][l]
    __shared__ float b0sh[256];
    __shared__ float b1sh[256];
    __shared__ float kred[4][16][17];               // wave, h_local, b_local

    const int tid  = threadIdx.x;
    const int bg   = blockIdx.x >> 3;               // batch group (0..31)
    const int ht   = blockIdx.x & 7;                // h tile (0..7) == XCD id
    const int w    = tid >> 6;
    const int lane = tid & 63;
    const int q    = lane >> 4;
    const int rr   = lane & 15;

    // ---------- phase 0: stage combo -> ysb (bf16), load g / biases ----------
    {
        const int r  = tid >> 4;
        const int c8 = (tid & 15) * 8;
        const float4* yp = reinterpret_cast<const float4*>(ycur + (bg * 16 + r) * 128 + c8);
        float4 a = yp[0], bq = yp[1];
        float v[8] = {a.x, a.y, a.z, a.w, bq.x, bq.y, bq.z, bq.w};
        if constexpr (STAGE >= 2) {
            constexpr float cf[5][5] = {
                {0.161f, 0.f, 0.f, 0.f, 0.f},
                {-0.008480655492356989f, 0.335480655492357f, 0.f, 0.f, 0.f},
                {2.8971530571054935f, -6.359448489975075f, 4.3622954328695815f, 0.f, 0.f},
                {5.325864828439257f, -11.748883564062828f, 7.4955393428898365f, -0.09249506636175525f, 0.f},
                {5.86145544294642f, -12.92096931784711f, 8.159367898576159f, -0.071584973281401f, -0.028269050394068383f}};
            #pragma unroll
            for (int kk = 0; kk < STAGE - 1; ++kk) {
                const float4* kp = reinterpret_cast<const float4*>(kbuf + kk * 65536 + (bg * 16 + r) * 128 + c8);
                float4 ka = kp[0], kb2 = kp[1];
                float kv[8] = {ka.x, ka.y, ka.z, ka.w, kb2.x, kb2.y, kb2.z, kb2.w};
                float c = DT * cf[STAGE - 2][kk];
                #pragma unroll
                for (int ii = 0; ii < 8; ++ii) v[ii] += c * kv[ii];
            }
        }
        short8 sv;
        #pragma unroll
        for (int ii = 0; ii < 8; ++ii) sv[ii] = f2bf(v[ii]);
        *reinterpret_cast<short8*>(&ysb[r * 136 + c8]) = sv;

        b0sh[tid] = b0[tid];
        b1sh[tid] = b1[tid];
        int r2 = tid >> 4, seg = tid & 15, l0 = seg * 4;
        if (l0 < 63) {
            int n = (l0 + 4 <= 63) ? 4 : (63 - l0);
            const float* gp = logsig + (bg * 16 + r2) * 16384 + idx * 64 + 1 + l0;
            const float* bp = b2 + (ht * 16 + r2) * 63 + l0;
            for (int ii = 0; ii < n; ++ii) {
                gsh[r2 * 65 + l0 + ii]  = gp[ii];
                b2sh[r2 * 65 + l0 + ii] = bp[ii];
            }
        }
    }
    __syncthreads();

    // ---------- phase 1: h1 = silu(W0 @ ys^T + b0) ----------
    #pragma unroll
    for (int oi = 0; oi < 4; ++oi) {
        int ot = w * 4 + oi;
        f32x4 acc = {0.f, 0.f, 0.f, 0.f};
        #pragma unroll
        for (int kc = 0; kc < 4; ++kc) {
            short8 af = *reinterpret_cast<const short8*>(W0p + (ot * 4 + kc) * 512 + lane * 8);
            short8 bf = *reinterpret_cast<const short8*>(&ysb[rr * 136 + kc * 32 + q * 8]);
            acc = __builtin_amdgcn_mfma_f32_16x16x32_bf16(af, bf, acc, 0, 0, 0);
        }
        int ob = ot * 16 + q * 4;
        float vv[4];
        #pragma unroll
        for (int jj = 0; jj < 4; ++jj) {
            float x = acc[jj] + b0sh[ob + jj];
            vv[jj] = x * __fdividef(1.f, 1.f + __expf(-x));
        }
        unsigned lo = (unsigned)(unsigned short)f2bf(vv[0]) | ((unsigned)(unsigned short)f2bf(vv[1]) << 16);
        unsigned hi = (unsigned)(unsigned short)f2bf(vv[2]) | ((unsigned)(unsigned short)f2bf(vv[3]) << 16);
        *reinterpret_cast<unsigned*>(&h1b[rr * 264 + ob])     = lo;
        *reinterpret_cast<unsigned*>(&h1b[rr * 264 + ob + 2]) = hi;
    }
    __syncthreads();

    // ---------- phase 2: h2 = silu(W1 @ h1^T + b1) ----------
    #pragma unroll
    for (int oi = 0; oi < 4; ++oi) {
        int ot = w * 4 + oi;
        f32x4 acc = {0.f, 0.f, 0.f, 0.f};
        #pragma unroll
        for (int kc = 0; kc < 8; ++kc) {
            short8 af = *reinterpret_cast<const short8*>(W1p + (ot * 8 + kc) * 512 + lane * 8);
            short8 bf = *reinterpret_cast<const short8*>(&h1b[rr * 264 + kc * 32 + q * 8]);
            acc = __builtin_amdgcn_mfma_f32_16x16x32_bf16(af, bf, acc, 0, 0, 0);
        }
        int ob = ot * 16 + q * 4;
        float vv[4];
        #pragma unroll
        for (int jj = 0; jj < 4; ++jj) {
            float x = acc[jj] + b1sh[ob + jj];
            vv[jj] = x * __fdividef(1.f, 1.f + __expf(-x));
        }
        unsigned lo = (unsigned)(unsigned short)f2bf(vv[0]) | ((unsigned)(unsigned short)f2bf(vv[1]) << 16);
        unsigned hi = (unsigned)(unsigned short)f2bf(vv[2]) | ((unsigned)(unsigned short)f2bf(vv[3]) << 16);
        *reinterpret_cast<unsigned*>(&h2b[rr * 264 + ob])     = lo;
        *reinterpret_cast<unsigned*>(&h2b[rr * 264 + ob + 2]) = hi;
    }
    __syncthreads();

    // ---------- phase 3: k_slice[b][h] = sum_l tanh(W2[h*63+l]·h2[b] + b2) * g[b][l] ----------
    float kacc[4] = {0.f, 0.f, 0.f, 0.f};
    for (int lv = w; lv < 63; lv += 4) {
        f32x4 acc = {0.f, 0.f, 0.f, 0.f};
        const short* wp = W2p + (size_t)((ht * 63 + lv) * 8) * 512 + lane * 8;
        #pragma unroll
        for (int kc = 0; kc < 8; ++kc) {
            short8 af = *reinterpret_cast<const short8*>(wp + kc * 512);
            short8 bf = *reinterpret_cast<const short8*>(&h2b[rr * 264 + kc * 32 + q * 8]);
            acc = __builtin_amdgcn_mfma_f32_16x16x32_bf16(af, bf, acc, 0, 0, 0);
        }
        float gv = gsh[rr * 65 + lv];
        #pragma unroll
        for (int jj = 0; jj < 4; ++jj) {
            float x = acc[jj] + b2sh[(q * 4 + jj) * 65 + lv];
            kacc[jj] += fast_tanh(x) * gv;
        }
    }
    #pragma unroll
    for (int jj = 0; jj < 4; ++jj) kred[w][q * 4 + jj][rr] = kacc[jj];
    __syncthreads();

    // ---------- epilogue: cross-wave reduce, store k (or y_new for stage 6) ----------
    {
        int bl = tid >> 4;    // batch local
        int hl = tid & 15;    // h local
        float s = kred[0][hl][bl] + kred[1][hl][bl] + kred[2][hl][bl] + kred[3][hl][bl];
        int gi = (bg * 16 + bl) * 128 + ht * 16 + hl;
        if constexpr (STAGE < 6) {
            kbuf[(STAGE - 1) * 65536 + gi] = s;
        } else {
            float k1v = kbuf[0 * 65536 + gi], k2v = kbuf[1 * 65536 + gi], k3v = kbuf[2 * 65536 + gi],
                  k4v = kbuf[3 * 65536 + gi], k5v = kbuf[4 * 65536 + gi];
            ynext[gi] = ycur[gi] + DT * (0.09646076681806523f * k1v + 0.01f * k2v
                        + 0.4798896504144996f * k3v + 1.379008574103742f * k4v
                        + (-3.290069515436081f) * k5v + 2.324710524099774f * s);
        }
    }
}

// ---------------- final: softmax(yf @ l2w^T + l2b) ----------------
__global__ void out_kernel(const float* __restrict__ yf, const float* __restrict__ l2w,
                           const float* __restrict__ l2b, float* __restrict__ out) {
    int b = blockIdx.x, t = threadIdx.x;   // 64 threads
    float ya = yf[b * 128 + t], yb = yf[b * 128 + 64 + t];
    __shared__ float lg[10];
    for (int c = 0; c < 10; ++c) {
        float p = ya * l2w[c * 128 + t] + yb * l2w[c * 128 + 64 + t];
        for (int off = 32; off > 0; off >>= 1) p += __shfl_down(p, off);
        if (t == 0) lg[c] = p + l2b[c];
    }
    __syncthreads();
    if (t == 0) {
        float m = lg[0];
        for (int c = 1; c < 10; ++c) m = fmaxf(m, lg[c]);
        float s = 0.f, e[10];
        for (int c = 0; c < 10; ++c) { e[c] = expf(lg[c] - m); s += e[c]; }
        for (int c = 0; c < 10; ++c) out[b * 10 + c] = e[c] / s;
    }
}

extern "C" void kernel_launch(void* const* d_in, const int* in_sizes, int n_in,
                              void* d_out, int out_size, void* d_ws, size_t ws_size,
                              hipStream_t stream) {
    const float* logsig = (const float*)d_in[2];
    const float* x0  = (const float*)d_in[3];
    const float* W0  = (const float*)d_in[4];
    const float* b0  = (const float*)d_in[5];
    const float* W1  = (const float*)d_in[6];
    const float* b1  = (const float*)d_in[7];
    const float* W2  = (const float*)d_in[8];
    const float* b2  = (const float*)d_in[9];
    const float* l1w = (const float*)d_in[10];
    const float* l1b = (const float*)d_in[11];
    const float* l2w = (const float*)d_in[12];
    const float* l2b = (const float*)d_in[13];
    float* out = (float*)d_out;

    char* ws = (char*)d_ws;
    float* yb0  = (float*)(ws);                    // 512x128 f32
    float* yb1  = (float*)(ws + 262144);
    float* kbuf = (float*)(ws + 524288);           // 6 x 512x128 f32
    short* W0p  = (short*)(ws + 2097152);          // 64 KB bf16
    short* W1p  = (short*)(ws + 2162688);          // 256 KB
    short* W2p  = (short*)(ws + 2424832);          // 4.13 MB

    perm_w0<<<128, 256, 0, stream>>>(W0, W0p);
    perm_w1<<<512, 256, 0, stream>>>(W1, W1p);
    perm_w2<<<8064, 256, 0, stream>>>(W2, W2p);
    y0_kernel<<<256, 256, 0, stream>>>(x0, l1w, l1b, yb0);

    for (int s = 0; s < NSTEPS; ++s) {
        float* yc = (s & 1) ? yb1 : yb0;
        float* yn = (s & 1) ? yb0 : yb1;
        int i1 = (s == 0) ? 0 : (s - 1);
        stage_kernel<1><<<256, 256, 0, stream>>>(yc, nullptr, kbuf, W0p, W1p, W2p, b0, b1, b2, logsig, i1);
        stage_kernel<2><<<256, 256, 0, stream>>>(yc, nullptr, kbuf, W0p, W1p, W2p, b0, b1, b2, logsig, s);
        stage_kernel<3><<<256, 256, 0, stream>>>(yc, nullptr, kbuf, W0p, W1p, W2p, b0, b1, b2, logsig, s);
        stage_kernel<4><<<256, 256, 0, stream>>>(yc, nullptr, kbuf, W0p, W1p, W2p, b0, b1, b2, logsig, s);
        stage_kernel<5><<<256, 256, 0, stream>>>(yc, nullptr, kbuf, W0p, W1p, W2p, b0, b1, b2, logsig, s);
        stage_kernel<6><<<256, 256, 0, stream>>>(yc, yn,      kbuf, W0p, W1p, W2p, b0, b1, b2, logsig, s);
    }
    out_kernel<<<512, 64, 0, stream>>>(yb0, l2w, l2b, out);
}

// Round 2
// 16286.804 us; speedup vs baseline: 1.6018x; 1.6018x over previous
//
#include <hip/hip_runtime.h>

typedef __attribute__((ext_vector_type(8))) short short8;
typedef __attribute__((ext_vector_type(4))) float f32x4;

#define DT (1.0f/256.0f)
#define NSTEPS 256

__device__ __forceinline__ short f2bf(float f) {
    unsigned u = __float_as_uint(f);
    u = (u + 0x7fffu + ((u >> 16) & 1u)) >> 16;
    return (short)u;
}

__device__ __forceinline__ float fast_tanh(float x) {
    float e = __expf(2.f * x);
    return 1.f - __fdividef(2.f, e + 1.f);
}

// ---------------- weight permutation (A-fragment order, bf16) ----------------
// A-frag for mfma_f32_16x16x32_bf16: lane l holds A[m = l&15][k = kc*32 + (l>>4)*8 + j], j=0..7
__global__ void perm_w0(const float* __restrict__ W0, short* __restrict__ W0p) {
    int i = blockIdx.x * 256 + threadIdx.x;            // 32768 = 16ot*4kc*64*8
    int j = i & 7, l = (i >> 3) & 63, kc = (i >> 9) & 3, ot = i >> 11;
    int row = ot * 16 + (l & 15);
    int col = kc * 32 + ((l >> 4) << 3) + j;
    W0p[i] = f2bf(W0[row * 128 + col]);
}
__global__ void perm_w1(const float* __restrict__ W1, short* __restrict__ W1p) {
    int i = blockIdx.x * 256 + threadIdx.x;            // 131072 = 16ot*8kc*64*8
    int j = i & 7, l = (i >> 3) & 63, kc = (i >> 9) & 7, ot = i >> 12;
    int row = ot * 16 + (l & 15);
    int col = kc * 32 + ((l >> 4) << 3) + j;
    W1p[i] = f2bf(W1[row * 256 + col]);
}
// padded: 64 lv rows per h-tile (row 63 zeroed)
__global__ void perm_w2(const float* __restrict__ W2, short* __restrict__ W2p) {
    int i = blockIdx.x * 256 + threadIdx.x;            // 2097152 = 8ht*64lv*8kc*64*8
    int j = i & 7, ln = (i >> 3) & 63, kc = (i >> 9) & 7;
    int v = i >> 12;                                   // ht*64 + lv
    int ht = v >> 6, lv = v & 63;
    if (lv == 63) { W2p[i] = 0; return; }
    int row = (ht * 16 + (ln & 15)) * 63 + lv;         // W2 row = h*63 + l
    int col = kc * 32 + ((ln >> 4) << 3) + j;
    W2p[i] = f2bf(W2[row * 256 + col]);
}

// ---------------- y0 = x0 @ l1w^T + l1b ----------------
__global__ void y0_kernel(const float* __restrict__ x0, const float* __restrict__ l1w,
                          const float* __restrict__ l1b, float* __restrict__ y) {
    int i = blockIdx.x * 256 + threadIdx.x;            // 65536
    int b = i >> 7, h = i & 127;
    float s = l1b[h];
    #pragma unroll
    for (int d = 0; d < 8; ++d) s += x0[b * 8 + d] * l1w[h * 8 + d];
    y[i] = s;
}

// ---------------- one RK stage ----------------
// grid 256 = 32 b-groups (16 rows each) x 8 h-tiles (16 h each); 512 threads (8 waves)
template<int STAGE>
__global__ __launch_bounds__(512, 2) void stage_kernel(
    const float* __restrict__ ycur, float* __restrict__ ynext,
    float* __restrict__ kbuf,
    const short* __restrict__ W0p, const short* __restrict__ W1p, const short* __restrict__ W2p,
    const float* __restrict__ b0, const float* __restrict__ b1, const float* __restrict__ b2,
    const float* __restrict__ logsig, int idx)
{
    __shared__ __align__(16) short ysb[16 * 136];   // stage input, bf16, padded stride
    __shared__ __align__(16) short h1b[16 * 264];
    __shared__ __align__(16) short h2b[16 * 264];
    __shared__ float gsh[16 * 65];                  // g[b_local][l]  (l=63 zeroed)
    __shared__ float b2sh[16 * 65];                 // b2[h_local][l] (l=63 zeroed)
    __shared__ float b0sh[256];
    __shared__ float b1sh[256];
    __shared__ float kred[8][16][17];               // wave, h_local, b_local

    const int tid  = threadIdx.x;
    const int bg   = blockIdx.x >> 3;               // batch group (0..31)
    const int ht   = blockIdx.x & 7;                // h tile (0..7) == XCD id
    const int w    = tid >> 6;                      // wave 0..7
    const int lane = tid & 63;
    const int q    = lane >> 4;
    const int rr   = lane & 15;

    // ---------- phase 0: stage combo -> ysb (bf16), load g / biases ----------
    if (tid < 256) {
        const int r  = tid >> 4;
        const int c8 = (tid & 15) * 8;
        const float4* yp = reinterpret_cast<const float4*>(ycur + (bg * 16 + r) * 128 + c8);
        float4 a = yp[0], bq = yp[1];
        float v[8] = {a.x, a.y, a.z, a.w, bq.x, bq.y, bq.z, bq.w};
        if constexpr (STAGE >= 2) {
            constexpr float cf[5][5] = {
                {0.161f, 0.f, 0.f, 0.f, 0.f},
                {-0.008480655492356989f, 0.335480655492357f, 0.f, 0.f, 0.f},
                {2.8971530571054935f, -6.359448489975075f, 4.3622954328695815f, 0.f, 0.f},
                {5.325864828439257f, -11.748883564062828f, 7.4955393428898365f, -0.09249506636175525f, 0.f},
                {5.86145544294642f, -12.92096931784711f, 8.159367898576159f, -0.071584973281401f, -0.028269050394068383f}};
            #pragma unroll
            for (int kk = 0; kk < STAGE - 1; ++kk) {
                const float4* kp = reinterpret_cast<const float4*>(kbuf + kk * 65536 + (bg * 16 + r) * 128 + c8);
                float4 ka = kp[0], kb2 = kp[1];
                float kv[8] = {ka.x, ka.y, ka.z, ka.w, kb2.x, kb2.y, kb2.z, kb2.w};
                float c = DT * cf[STAGE - 2][kk];
                #pragma unroll
                for (int ii = 0; ii < 8; ++ii) v[ii] += c * kv[ii];
            }
        }
        short8 sv;
        #pragma unroll
        for (int ii = 0; ii < 8; ++ii) sv[ii] = f2bf(v[ii]);
        *reinterpret_cast<short8*>(&ysb[r * 136 + c8]) = sv;
    } else {
        const int t2 = tid - 256;
        b0sh[t2] = b0[t2];
        b1sh[t2] = b1[t2];
        int r2 = t2 >> 4, seg = t2 & 15, l0 = seg * 4;
        if (l0 < 63) {
            int n = (l0 + 4 <= 63) ? 4 : (63 - l0);
            const float* gp = logsig + (bg * 16 + r2) * 16384 + idx * 64 + 1 + l0;
            const float* bp = b2 + (ht * 16 + r2) * 63 + l0;
            for (int ii = 0; ii < n; ++ii) {
                gsh[r2 * 65 + l0 + ii]  = gp[ii];
                b2sh[r2 * 65 + l0 + ii] = bp[ii];
            }
            if (seg == 15) {           // zero the lv=63 pad slot
                gsh[r2 * 65 + 63]  = 0.f;
                b2sh[r2 * 65 + 63] = 0.f;
            }
        }
    }
    __syncthreads();

    // ---------- phase 1: h1 = silu(W0 @ ys^T + b0) ----------
    #pragma unroll
    for (int oi = 0; oi < 2; ++oi) {
        int ot = w * 2 + oi;
        f32x4 acc0 = {0.f, 0.f, 0.f, 0.f}, acc1 = {0.f, 0.f, 0.f, 0.f};
        #pragma unroll
        for (int kc = 0; kc < 2; ++kc) {
            short8 af0 = *reinterpret_cast<const short8*>(W0p + (ot * 4 + kc) * 512 + lane * 8);
            short8 bf0 = *reinterpret_cast<const short8*>(&ysb[rr * 136 + kc * 32 + q * 8]);
            acc0 = __builtin_amdgcn_mfma_f32_16x16x32_bf16(af0, bf0, acc0, 0, 0, 0);
            short8 af1 = *reinterpret_cast<const short8*>(W0p + (ot * 4 + kc + 2) * 512 + lane * 8);
            short8 bf1 = *reinterpret_cast<const short8*>(&ysb[rr * 136 + (kc + 2) * 32 + q * 8]);
            acc1 = __builtin_amdgcn_mfma_f32_16x16x32_bf16(af1, bf1, acc1, 0, 0, 0);
        }
        int ob = ot * 16 + q * 4;
        float vv[4];
        #pragma unroll
        for (int jj = 0; jj < 4; ++jj) {
            float x = acc0[jj] + acc1[jj] + b0sh[ob + jj];
            vv[jj] = x * __fdividef(1.f, 1.f + __expf(-x));
        }
        unsigned lo = (unsigned)(unsigned short)f2bf(vv[0]) | ((unsigned)(unsigned short)f2bf(vv[1]) << 16);
        unsigned hi = (unsigned)(unsigned short)f2bf(vv[2]) | ((unsigned)(unsigned short)f2bf(vv[3]) << 16);
        *reinterpret_cast<unsigned*>(&h1b[rr * 264 + ob])     = lo;
        *reinterpret_cast<unsigned*>(&h1b[rr * 264 + ob + 2]) = hi;
    }
    __syncthreads();

    // ---------- phase 2: h2 = silu(W1 @ h1^T + b1) ----------
    #pragma unroll
    for (int oi = 0; oi < 2; ++oi) {
        int ot = w * 2 + oi;
        f32x4 acc0 = {0.f, 0.f, 0.f, 0.f}, acc1 = {0.f, 0.f, 0.f, 0.f};
        #pragma unroll
        for (int kc = 0; kc < 4; ++kc) {
            short8 af0 = *reinterpret_cast<const short8*>(W1p + (ot * 8 + kc) * 512 + lane * 8);
            short8 bf0 = *reinterpret_cast<const short8*>(&h1b[rr * 264 + kc * 32 + q * 8]);
            acc0 = __builtin_amdgcn_mfma_f32_16x16x32_bf16(af0, bf0, acc0, 0, 0, 0);
            short8 af1 = *reinterpret_cast<const short8*>(W1p + (ot * 8 + kc + 4) * 512 + lane * 8);
            short8 bf1 = *reinterpret_cast<const short8*>(&h1b[rr * 264 + (kc + 4) * 32 + q * 8]);
            acc1 = __builtin_amdgcn_mfma_f32_16x16x32_bf16(af1, bf1, acc1, 0, 0, 0);
        }
        int ob = ot * 16 + q * 4;
        float vv[4];
        #pragma unroll
        for (int jj = 0; jj < 4; ++jj) {
            float x = acc0[jj] + acc1[jj] + b1sh[ob + jj];
            vv[jj] = x * __fdividef(1.f, 1.f + __expf(-x));
        }
        unsigned lo = (unsigned)(unsigned short)f2bf(vv[0]) | ((unsigned)(unsigned short)f2bf(vv[1]) << 16);
        unsigned hi = (unsigned)(unsigned short)f2bf(vv[2]) | ((unsigned)(unsigned short)f2bf(vv[3]) << 16);
        *reinterpret_cast<unsigned*>(&h2b[rr * 264 + ob])     = lo;
        *reinterpret_cast<unsigned*>(&h2b[rr * 264 + ob + 2]) = hi;
    }
    __syncthreads();

    // ---------- phase 3: k_slice[b][h] = sum_l tanh(W2[h*63+l]·h2[b] + b2) * g[b][l] ----------
    // wave w owns lv in [w*8, w*8+8); lv=63 is a zero pad. 4 independent MFMA chains of depth 4.
    float kacc[4] = {0.f, 0.f, 0.f, 0.f};
    const int lvbase = w * 8;
    #pragma unroll
    for (int i2 = 0; i2 < 4; ++i2) {
        const int lvA = lvbase + i2 * 2;
        const int lvB = lvA + 1;
        f32x4 aA0 = {0.f,0.f,0.f,0.f}, aA1 = {0.f,0.f,0.f,0.f};
        f32x4 aB0 = {0.f,0.f,0.f,0.f}, aB1 = {0.f,0.f,0.f,0.f};
        const short* wpA = W2p + (size_t)((ht * 64 + lvA) * 8) * 512 + lane * 8;
        const short* wpB = wpA + 8 * 512;
        #pragma unroll
        for (int kc = 0; kc < 4; ++kc) {
            short8 bf0 = *reinterpret_cast<const short8*>(&h2b[rr * 264 + kc * 32 + q * 8]);
            short8 bf1 = *reinterpret_cast<const short8*>(&h2b[rr * 264 + (kc + 4) * 32 + q * 8]);
            aA0 = __builtin_amdgcn_mfma_f32_16x16x32_bf16(*reinterpret_cast<const short8*>(wpA + kc * 512),       bf0, aA0, 0, 0, 0);
            aA1 = __builtin_amdgcn_mfma_f32_16x16x32_bf16(*reinterpret_cast<const short8*>(wpA + (kc + 4) * 512), bf1, aA1, 0, 0, 0);
            aB0 = __builtin_amdgcn_mfma_f32_16x16x32_bf16(*reinterpret_cast<const short8*>(wpB + kc * 512),       bf0, aB0, 0, 0, 0);
            aB1 = __builtin_amdgcn_mfma_f32_16x16x32_bf16(*reinterpret_cast<const short8*>(wpB + (kc + 4) * 512), bf1, aB1, 0, 0, 0);
        }
        float gA = gsh[rr * 65 + lvA];
        float gB = gsh[rr * 65 + lvB];
        #pragma unroll
        for (int jj = 0; jj < 4; ++jj) {
            float xA = aA0[jj] + aA1[jj] + b2sh[(q * 4 + jj) * 65 + lvA];
            kacc[jj] += fast_tanh(xA) * gA;
            float xB = aB0[jj] + aB1[jj] + b2sh[(q * 4 + jj) * 65 + lvB];
            kacc[jj] += fast_tanh(xB) * gB;
        }
    }
    #pragma unroll
    for (int jj = 0; jj < 4; ++jj) kred[w][q * 4 + jj][rr] = kacc[jj];
    __syncthreads();

    // ---------- epilogue: cross-wave reduce, store k (or y_new for stage 6) ----------
    if (tid < 256) {
        int bl = tid >> 4;    // batch local
        int hl = tid & 15;    // h local
        float s = kred[0][hl][bl] + kred[1][hl][bl] + kred[2][hl][bl] + kred[3][hl][bl]
                + kred[4][hl][bl] + kred[5][hl][bl] + kred[6][hl][bl] + kred[7][hl][bl];
        int gi = (bg * 16 + bl) * 128 + ht * 16 + hl;
        if constexpr (STAGE < 6) {
            kbuf[(STAGE - 1) * 65536 + gi] = s;
        } else {
            float k1v = kbuf[0 * 65536 + gi], k2v = kbuf[1 * 65536 + gi], k3v = kbuf[2 * 65536 + gi],
                  k4v = kbuf[3 * 65536 + gi], k5v = kbuf[4 * 65536 + gi];
            ynext[gi] = ycur[gi] + DT * (0.09646076681806523f * k1v + 0.01f * k2v
                        + 0.4798896504144996f * k3v + 1.379008574103742f * k4v
                        + (-3.290069515436081f) * k5v + 2.324710524099774f * s);
        }
    }
}

// ---------------- final: softmax(yf @ l2w^T + l2b) ----------------
__global__ void out_kernel(const float* __restrict__ yf, const float* __restrict__ l2w,
                           const float* __restrict__ l2b, float* __restrict__ out) {
    int b = blockIdx.x, t = threadIdx.x;   // 64 threads
    float ya = yf[b * 128 + t], yb = yf[b * 128 + 64 + t];
    __shared__ float lg[10];
    for (int c = 0; c < 10; ++c) {
        float p = ya * l2w[c * 128 + t] + yb * l2w[c * 128 + 64 + t];
        for (int off = 32; off > 0; off >>= 1) p += __shfl_down(p, off);
        if (t == 0) lg[c] = p + l2b[c];
    }
    __syncthreads();
    if (t == 0) {
        float m = lg[0];
        for (int c = 1; c < 10; ++c) m = fmaxf(m, lg[c]);
        float s = 0.f, e[10];
        for (int c = 0; c < 10; ++c) { e[c] = expf(lg[c] - m); s += e[c]; }
        for (int c = 0; c < 10; ++c) out[b * 10 + c] = e[c] / s;
    }
}

extern "C" void kernel_launch(void* const* d_in, const int* in_sizes, int n_in,
                              void* d_out, int out_size, void* d_ws, size_t ws_size,
                              hipStream_t stream) {
    const float* logsig = (const float*)d_in[2];
    const float* x0  = (const float*)d_in[3];
    const float* W0  = (const float*)d_in[4];
    const float* b0  = (const float*)d_in[5];
    const float* W1  = (const float*)d_in[6];
    const float* b1  = (const float*)d_in[7];
    const float* W2  = (const float*)d_in[8];
    const float* b2  = (const float*)d_in[9];
    const float* l1w = (const float*)d_in[10];
    const float* l1b = (const float*)d_in[11];
    const float* l2w = (const float*)d_in[12];
    const float* l2b = (const float*)d_in[13];
    float* out = (float*)d_out;

    char* ws = (char*)d_ws;
    float* yb0  = (float*)(ws);                    // 512x128 f32
    float* yb1  = (float*)(ws + 262144);
    float* kbuf = (float*)(ws + 524288);           // 6 x 512x128 f32
    short* W0p  = (short*)(ws + 2097152);          // 64 KB bf16
    short* W1p  = (short*)(ws + 2162688);          // 256 KB
    short* W2p  = (short*)(ws + 2424832);          // 4 MB (padded 8*64*8*512)

    perm_w0<<<128, 256, 0, stream>>>(W0, W0p);
    perm_w1<<<512, 256, 0, stream>>>(W1, W1p);
    perm_w2<<<8192, 256, 0, stream>>>(W2, W2p);
    y0_kernel<<<256, 256, 0, stream>>>(x0, l1w, l1b, yb0);

    for (int s = 0; s < NSTEPS; ++s) {
        float* yc = (s & 1) ? yb1 : yb0;
        float* yn = (s & 1) ? yb0 : yb1;
        int i1 = (s == 0) ? 0 : (s - 1);
        stage_kernel<1><<<256, 512, 0, stream>>>(yc, nullptr, kbuf, W0p, W1p, W2p, b0, b1, b2, logsig, i1);
        stage_kernel<2><<<256, 512, 0, stream>>>(yc, nullptr, kbuf, W0p, W1p, W2p, b0, b1, b2, logsig, s);
        stage_kernel<3><<<256, 512, 0, stream>>>(yc, nullptr, kbuf, W0p, W1p, W2p, b0, b1, b2, logsig, s);
        stage_kernel<4><<<256, 512, 0, stream>>>(yc, nullptr, kbuf, W0p, W1p, W2p, b0, b1, b2, logsig, s);
        stage_kernel<5><<<256, 512, 0, stream>>>(yc, nullptr, kbuf, W0p, W1p, W2p, b0, b1, b2, logsig, s);
        stage_kernel<6><<<256, 512, 0, stream>>>(yc, yn,      kbuf, W0p, W1p, W2p, b0, b1, b2, logsig, s);
    }
    out_kernel<<<512, 64, 0, stream>>>(yb0, l2w, l2b, out);
}